// Round 8
// baseline (4194.839 us; speedup 1.0000x reference)
//
#include <hip/hip_runtime.h>

#define NT 1024
#define NB 256            // 256 blocks x 1024 thr = 262144 = n; 1 block/CU
#define MAXIT 100
#define RTOL_F 1e-5f
// SELL-64x1: slice = 64 rows = one wave, 1 lane per row.
// entry j of row -> sell[soff[slice] + j*64 + (row & 63)]
//
// Chronopoulos-Gear CG, 2 flag barriers/iter.
//  - r is CACHED: owner publishes with plain stores; the r-publish barrier is
//    release(wbl2) -> flags -> acquire(inv), once per iteration. Gathers are
//    then plain loads with ~94% L2 hit rate (r = 4 MB = one XCD L2; ~128
//    touches per 128B line per iteration).
//  - partials/flags stay on the uncached agent-atomic path (immune to the inv).
//  - spin loops are RELAXED only (round-4 lesson: acquire-in-spin = storm).

typedef float f4 __attribute__((ext_vector_type(4)));

__device__ __forceinline__ unsigned long long pk2(float a, float b) {
    return ((unsigned long long)__float_as_uint(b) << 32) | (unsigned long long)__float_as_uint(a);
}

// ---- distributed flag barrier ----
// Each block publishes flags[b]=seq (own slot); wave 0 polls all NB flags.
// __syncthreads() drains vmcnt first, so all prior stores are issued before
// the flag goes up (coherence per-variant below).
__device__ __forceinline__ void fbar(int* flags, int seq) {
    __syncthreads();
    if (threadIdx.x == 0)
        __hip_atomic_store(&flags[blockIdx.x], seq, __ATOMIC_RELAXED, __HIP_MEMORY_SCOPE_AGENT);
    if (threadIdx.x < 64) {
        const int b4 = threadIdx.x << 2;
        for (;;) {
            const int f0 = __hip_atomic_load(&flags[b4 + 0], __ATOMIC_RELAXED, __HIP_MEMORY_SCOPE_AGENT);
            const int f1 = __hip_atomic_load(&flags[b4 + 1], __ATOMIC_RELAXED, __HIP_MEMORY_SCOPE_AGENT);
            const int f2 = __hip_atomic_load(&flags[b4 + 2], __ATOMIC_RELAXED, __HIP_MEMORY_SCOPE_AGENT);
            const int f3 = __hip_atomic_load(&flags[b4 + 3], __ATOMIC_RELAXED, __HIP_MEMORY_SCOPE_AGENT);
            const bool ok = (f0 >= seq) && (f1 >= seq) && (f2 >= seq) && (f3 >= seq);
            if (__all(ok)) break;
            __builtin_amdgcn_s_sleep(1);
        }
    }
    __syncthreads();
}

// heavy: full agent cache maintenance around arrival (release=wbl2, acquire=inv).
// Fences run exactly once; the spin inside fbar stays relaxed.
__device__ __forceinline__ void fbar_heavy(int* flags, int seq) {
    __builtin_amdgcn_fence(__ATOMIC_RELEASE, "agent");
    fbar(flags, seq);
    __builtin_amdgcn_fence(__ATOMIC_ACQUIRE, "agent");
}

// Block-wide sum of two floats, broadcast to all threads (deterministic order).
__device__ __forceinline__ float2 block_sum2_bcast(float a, float b, float* smf) {
#pragma unroll
    for (int o = 32; o > 0; o >>= 1) { a += __shfl_down(a, o); b += __shfl_down(b, o); }
    __syncthreads();
    const int w = threadIdx.x >> 6;
    if ((threadIdx.x & 63) == 0) { smf[w] = a; smf[16 + w] = b; }
    __syncthreads();
    float ra = 0.f, rb = 0.f;
#pragma unroll
    for (int i = 0; i < 16; ++i) { ra += smf[i]; rb += smf[16 + i]; }
    return make_float2(ra, rb);
}

// Sum the NB packed (rho,mu) per-block partials — identical in every block.
__device__ __forceinline__ float2 sum_parts2(const unsigned long long* part, float* smf) {
    float a = 0.f, b = 0.f;
    if (threadIdx.x < NB) {
        unsigned long long u = __hip_atomic_load(&part[threadIdx.x], __ATOMIC_RELAXED,
                                                 __HIP_MEMORY_SCOPE_AGENT);
        a = __uint_as_float((unsigned)(u & 0xffffffffu));
        b = __uint_as_float((unsigned)(u >> 32));
    }
    return block_sum2_bcast(a, b, smf);
}

// Inclusive scan of one int per thread across the block (NT), via LDS.
__device__ __forceinline__ int block_incl_scan(int v, int* smi) {
    const int t = threadIdx.x;
    smi[t] = v;
    __syncthreads();
    for (int off = 1; off < NT; off <<= 1) {
        int add = (t >= off) ? smi[t - off] : 0;
        __syncthreads();
        v += add;
        smi[t] = v;
        __syncthreads();
    }
    return v;
}

// One SELL row SpMV, unroll-8 (J multiple of 8). Cached gathers: compiler
// schedules 8 sell loads + 8 r loads with fine-grained waitcnt; r lines are
// L2-resident after first touch (~16 reuses/row/iter).
__device__ __forceinline__ f4 spmv_row(const long long* __restrict__ bp0, int J,
                                       const f4* __restrict__ rq) {
    f4 a4 = {0.f, 0.f, 0.f, 0.f};
    for (int j = 0; j < J; j += 8) {
        long long e[8];
#pragma unroll
        for (int u = 0; u < 8; ++u) e[u] = bp0[(j + u) * 64];
        f4 g[8];
#pragma unroll
        for (int u = 0; u < 8; ++u) g[u] = rq[(int)(e[u] & 0xffffffffLL)];
#pragma unroll
        for (int u = 0; u < 8; ++u) {
            const float v = __int_as_float((int)(e[u] >> 32));
            a4 += v * g[u];
        }
    }
    return a4;
}

__global__ void __launch_bounds__(NT, 4)
cg_solver_kernel(const float* __restrict__ values,
                 const f4* __restrict__ bvec,
                 const int* __restrict__ rowi,
                 const int* __restrict__ coli,
                 f4* __restrict__ x,                   // = d_out
                 f4* __restrict__ rst,                 // r rows (cached; coherence via fences)
                 int* __restrict__ counts,
                 int* __restrict__ ridx,
                 int* __restrict__ jarr,
                 int* __restrict__ soff,
                 unsigned long long* __restrict__ part, // NB packed (rho,mu) partials
                 int* __restrict__ flags,               // NB barrier flags (memset 0)
                 long long* __restrict__ sell,
                 int n, int nnz, int nslice)
{
    const int t = threadIdx.x;
    const int tid = blockIdx.x * NT + t;
    const int nth = gridDim.x * NT;          // == n
    __shared__ int smi[NT];
    __shared__ float smf[32];
    int seq = 0;

    // ---- Phase A: zero counters ----
    for (int i = tid; i < n; i += nth) { counts[i] = 0; ridx[i] = 0; }
    fbar_heavy(flags, ++seq);

    // ---- Phase B: histogram + keep b in registers; publish r=b ----
    for (int e = tid; e < nnz; e += nth) atomicAdd(&counts[rowi[e]], 1);
    f4 rv = bvec[tid];                       // r_0 = b (register-resident)
    rst[tid] = rv;
    fbar_heavy(flags, ++seq);

    // ---- Phase C: per-slice padded slot count (multiple of 8 for unroll-8) ----
    for (int s = tid; s < nslice; s += nth) {
        const int rb = s << 6;
        int m = 0;
#pragma unroll 4
        for (int i = 0; i < 64; ++i) m = max(m, counts[rb + i]);
        jarr[s] = (m + 7) & ~7;
    }
    fbar_heavy(flags, ++seq);

    // ---- Phase D: block 0 scans slice sizes -> soff ----
    if (blockIdx.x == 0) {
        const int spt = (nslice + NT - 1) / NT;
        const int base = t * spt;
        int local = 0;
        for (int i = 0; i < spt; ++i) {
            int s = base + i;
            if (s < nslice) local += 64 * jarr[s];
        }
        int incl = block_incl_scan(local, smi);
        int run = incl - local;
        for (int i = 0; i < spt; ++i) {
            int s = base + i;
            if (s < nslice) { soff[s] = run; run += 64 * jarr[s]; }
        }
        if (t == NT - 1) soff[nslice] = incl;
    }
    fbar_heavy(flags, ++seq);

    // ---- Phase E: zero-fill SELL ----
    {
        const int total = soff[nslice];
        for (int i = tid; i < total; i += nth) sell[i] = 0LL;
    }
    fbar_heavy(flags, ++seq);

    // ---- Phase F: scatter COO -> SELL ----
    for (int e = tid; e < nnz; e += nth) {
        const int rr = rowi[e];
        const int i = atomicAdd(&ridx[rr], 1);
        const int pos = soff[rr >> 6] + (i << 6) + (rr & 63);
        sell[pos] = ((long long)__float_as_int(values[e]) << 32) | (unsigned int)coli[e];
    }
    fbar_heavy(flags, ++seq);   // acquire-inv => caches clean before first gathers

    // ---- CG-CG state (owner-local state in registers; x written once at end) ----
    const int wid = tid >> 6;
    const int lane = t & 63;
    const long long* __restrict__ bp0 = sell + soff[wid] + lane;
    const int J = jarr[wid];
    const f4* __restrict__ rq = rst;

    f4 pv = {0.f, 0.f, 0.f, 0.f};
    f4 sv = {0.f, 0.f, 0.f, 0.f};
    f4 xv = {0.f, 0.f, 0.f, 0.f};
    f4 wv;

    // ---- init-S: w0 = A r0; rho0 = r.r, mu0 = r.w ----
    {
        wv = spmv_row(bp0, J, rq);
        float rho_p = rv.x * rv.x + rv.y * rv.y + rv.z * rv.z + rv.w * rv.w;
        float mu_p  = rv.x * wv.x + rv.y * wv.y + rv.z * wv.z + rv.w * wv.w;
        float2 tot = block_sum2_bcast(rho_p, mu_p, smf);
        if (t == 0)
            __hip_atomic_store(&part[blockIdx.x], pk2(tot.x, tot.y), __ATOMIC_RELAXED, __HIP_MEMORY_SCOPE_AGENT);
    }
    fbar(flags, ++seq);

    float2 rm = sum_parts2(part, smf);       // (rho0, mu0) — identical in all blocks
    float rho = rm.x;
    const float tol2 = RTOL_F * RTOL_F * rho;
    float alpha = rho / rm.y;
    float beta = 0.f;

    int k = 0;
    while (rho > tol2 && k < MAXIT) {
        // --- U: register recurrences; publish new r (cached store) ---
        pv = rv + beta * pv;
        sv = wv + beta * sv;
        xv = xv + alpha * pv;
        rv = rv - alpha * sv;
        rst[tid] = rv;
        // release(wbl2: flush dirty r) -> barrier -> acquire(inv: drop stale r)
        fbar_heavy(flags, ++seq);

        // --- S: w = A r (L2-cached gathers) + fused (r.r, r.w) partials ---
        wv = spmv_row(bp0, J, rq);
        {
            float rho_p = rv.x * rv.x + rv.y * rv.y + rv.z * rv.z + rv.w * rv.w;
            float mu_p  = rv.x * wv.x + rv.y * wv.y + rv.z * wv.z + rv.w * wv.w;
            float2 tot = block_sum2_bcast(rho_p, mu_p, smf);
            if (t == 0)
                __hip_atomic_store(&part[blockIdx.x], pk2(tot.x, tot.y), __ATOMIC_RELAXED, __HIP_MEMORY_SCOPE_AGENT);
        }
        fbar(flags, ++seq);   // partials published => all gathers of r_k done

        // --- scalars: identical in every block ---
        rm = sum_parts2(part, smf);          // (rho_{k+1}, mu_{k+1})
        beta = rm.x / rho;
        alpha = rm.x / (rm.y - beta * rm.x / alpha);
        rho = rm.x;
        ++k;
    }

    x[tid] = xv;   // single write of the solution
}

extern "C" void kernel_launch(void* const* d_in, const int* in_sizes, int n_in,
                              void* d_out, int out_size, void* d_ws, size_t ws_size,
                              hipStream_t stream) {
    const float* values = (const float*)d_in[0];
    const f4* bvec      = (const f4*)d_in[1];
    const int* rowi     = (const int*)d_in[2];
    const int* coli     = (const int*)d_in[3];
    const int nnz = in_sizes[0];
    const int n   = in_sizes[1] / 4;  // F = 4
    const int nslice = n / 64;

    char* ws = (char*)d_ws;
    size_t off = 0;
    auto alloc = [&](size_t bytes) -> void* {
        off = (off + 255) & ~(size_t)255;
        void* pp = ws + off;
        off += bytes;
        return pp;
    };
    int* flags   = (int*)alloc((size_t)NB * 4);       // barrier flags (memset 0)
    f4* rst      = (f4*)alloc((size_t)n * 16);
    unsigned long long* part = (unsigned long long*)alloc((size_t)NB * 8);
    int* counts  = (int*)alloc((size_t)n * 4);
    int* ridx    = (int*)alloc((size_t)n * 4);
    int* jarr    = (int*)alloc((size_t)nslice * 4);
    int* soff    = (int*)alloc((size_t)(nslice + 1) * 4);
    off = (off + 255) & ~(size_t)255;
    long long* sell = (long long*)(ws + off);         // rest of ws (~65 MB)
    f4* x = (f4*)d_out;

    hipMemsetAsync(flags, 0, (size_t)NB * 4, stream);

    int n_ = n, nnz_ = nnz, nslice_ = nslice;
    void* args[] = {
        (void*)&values, (void*)&bvec, (void*)&rowi, (void*)&coli,
        (void*)&x, (void*)&rst,
        (void*)&counts, (void*)&ridx, (void*)&jarr, (void*)&soff,
        (void*)&part, (void*)&flags,
        (void*)&sell, (void*)&n_, (void*)&nnz_, (void*)&nslice_
    };
    hipLaunchCooperativeKernel((void*)cg_solver_kernel, dim3(NB), dim3(NT),
                               args, 0, stream);
}